// Round 1
// baseline (9010.603 us; speedup 1.0000x reference)
//
#include <hip/hip_runtime.h>

#define N_USER 100000
#define M_ITEM 50000
#define N_NODE 150000
#define D 64
#define WD 32
#define B_SEED 2048
#define S_NB 20

// ---------------------------------------------------------------------------
// Node-embedding projection:  x[node] = concat(...) @ Wproj + bproj
//                                      + numeric @ Wnum + bnum
// Treated as GEMM [64 nodes x KTOT] @ [KTOT x 64]; A built on the fly.
// K layout (users, KTOT=534):  [0,64) id | [64,128) feat-mean | [128,224) text
//                              | [224,524) word300 | [524,534) numeric
// items (KTOT=1302): ... | [224,524) word300 | [524,1292) sent768 | [1292,1302) numeric
// ---------------------------------------------------------------------------
template<int IS_ITEM>
__global__ __launch_bounds__(256) void proj_kernel(
    const float* __restrict__ id_emb,
    const int*   __restrict__ feat_idx,
    const float* __restrict__ feat_emb,
    const int*   __restrict__ text_idx,
    const float* __restrict__ word_emb,
    const float* __restrict__ word300,
    const float* __restrict__ sent768,
    const float* __restrict__ numeric,
    const float* __restrict__ Wproj,
    const float* __restrict__ bproj,
    const float* __restrict__ Wnum,
    const float* __restrict__ bnum,
    float* __restrict__ xout,
    int ntype)
{
    const int KPROJ = IS_ITEM ? 1292 : 524;
    const int KTOT  = KPROJ + 10;
    const int NCHUNK = (KTOT + 63) / 64;

    __shared__ float A[64 * 64];   // [node within block][kk]

    const int t    = threadIdx.x;
    const int wave = t >> 6;
    const int lane = t & 63;       // output dim d
    const int nb   = blockIdx.x * 64;

    float acc[16];
#pragma unroll
    for (int i = 0; i < 16; ++i) acc[i] = 0.f;

    for (int c = 0; c < NCHUNK; ++c) {
        const int k0 = c * 64;
        __syncthreads();
        // ---- stage A chunk: thread t handles kk = t%64, nodes n = t/64 + 4i
        {
            const int kk = t & 63;
            const int k  = k0 + kk;
#pragma unroll
            for (int i = 0; i < 16; ++i) {
                const int n    = (t >> 6) + i * 4;
                const int node = nb + n;
                float v = 0.f;
                if (node < ntype && k < KTOT) {
                    if (k < 64) {
                        v = id_emb[node * 64 + k];
                    } else if (k < 128) {
                        const int* fi = feat_idx + node * 10;
                        float s = 0.f;
#pragma unroll
                        for (int j = 0; j < 10; ++j) s += feat_emb[fi[j] * 64 + (k - 64)];
                        v = s * 0.1f;
                    } else if (k < 224) {
                        const int kk2 = k - 128;
                        const int src = kk2 >> 5, wi = kk2 & 31;
                        const int* ti = text_idx + (node * 3 + src) * 8;
                        float s = 0.f;
#pragma unroll
                        for (int j = 0; j < 8; ++j) s += word_emb[ti[j] * 32 + wi];
                        v = s * 0.125f;
                    } else if (k < 524) {
                        v = word300[node * 300 + (k - 224)];
                    } else if (IS_ITEM && k < 1292) {
                        v = sent768[node * 768 + (k - 524)];
                    } else {
                        v = numeric[node * 10 + (k - KPROJ)];
                    }
                }
                A[n * 64 + kk] = v;
            }
        }
        __syncthreads();
        // ---- compute: wave handles nodes [wave*16, wave*16+16), lane = out dim
        for (int kk0 = 0; kk0 < 64; kk0 += 16) {
            float wv[16];
#pragma unroll
            for (int j = 0; j < 16; ++j) {
                const int k = k0 + kk0 + j;
                float w = 0.f;
                if (k < KTOT)
                    w = (k < KPROJ) ? Wproj[k * 64 + lane] : Wnum[(k - KPROJ) * 64 + lane];
                wv[j] = w;
            }
#pragma unroll
            for (int n = 0; n < 16; ++n) {
                const float* arow = &A[(wave * 16 + n) * 64 + kk0];
                const float4 a0 = reinterpret_cast<const float4*>(arow)[0];
                const float4 a1 = reinterpret_cast<const float4*>(arow)[1];
                const float4 a2 = reinterpret_cast<const float4*>(arow)[2];
                const float4 a3 = reinterpret_cast<const float4*>(arow)[3];
                acc[n] += a0.x*wv[0]  + a0.y*wv[1]  + a0.z*wv[2]  + a0.w*wv[3]
                        + a1.x*wv[4]  + a1.y*wv[5]  + a1.z*wv[6]  + a1.w*wv[7]
                        + a2.x*wv[8]  + a2.y*wv[9]  + a2.z*wv[10] + a2.w*wv[11]
                        + a3.x*wv[12] + a3.y*wv[13] + a3.z*wv[14] + a3.w*wv[15];
            }
        }
    }
    // ---- epilogue
    const float bias = bproj[lane] + bnum[lane];
#pragma unroll
    for (int n = 0; n < 16; ++n) {
        const int node = nb + wave * 16 + n;
        if (node < ntype) xout[node * 64 + lane] = acc[n] + bias;
    }
}

// ---------------------------------------------------------------------------
// Fused SAGE layer: per row r
//   m    = mean_j neigh_src[neigh_idx[r*S+j]]        (or rows r*S+j if idx==NULL)
//   agg  = m @ Wv + bv
//   h    = concat(self, agg) @ Ww + bw ; optional relu
// One wave per row; W staged in LDS; row broadcasts via __shfl.
// ---------------------------------------------------------------------------
template<int RELU>
__global__ __launch_bounds__(256) void sage_kernel(
    const float* __restrict__ self_src, const int* __restrict__ self_idx,
    const float* __restrict__ neigh_src, const int* __restrict__ neigh_idx,
    const float* __restrict__ Wv, const float* __restrict__ bv,
    const float* __restrict__ Ww, const float* __restrict__ bw,
    float* __restrict__ out, int nrows)
{
    __shared__ float WvL[64 * 64];
    __shared__ float WwL[128 * 64];
    const int t = threadIdx.x;
    for (int i = t; i < 64 * 64; i += 256)  WvL[i] = Wv[i];
    for (int i = t; i < 128 * 64; i += 256) WwL[i] = Ww[i];
    __syncthreads();

    const int wave = t >> 6, lane = t & 63;
    const int RPW  = 8;
    const int base = blockIdx.x * (4 * RPW) + wave * RPW;
    const float bvl = bv[lane], bwl = bw[lane];

    for (int i = 0; i < RPW; ++i) {
        const int r = base + i;
        if (r >= nrows) break;                       // wave-uniform guard
        const int sidx = self_idx ? self_idx[r] : r;
        const float selfv = self_src[sidx * 64 + lane];
        float mv = 0.f;
#pragma unroll
        for (int j = 0; j < S_NB; ++j) {
            const int nr = neigh_idx ? neigh_idx[r * S_NB + j] : (r * S_NB + j);
            mv += neigh_src[nr * 64 + lane];
        }
        mv *= (1.f / S_NB);

        float agg = bvl;
#pragma unroll 8
        for (int k = 0; k < 64; ++k)
            agg += __shfl(mv, k) * WvL[k * 64 + lane];

        float h = bwl;
#pragma unroll 8
        for (int k = 0; k < 64; ++k)
            h += __shfl(selfv, k) * WwL[k * 64 + lane];
#pragma unroll 8
        for (int k = 0; k < 64; ++k)
            h += __shfl(agg, k) * WwL[(64 + k) * 64 + lane];

        if (RELU) h = fmaxf(h, 0.f);
        out[r * 64 + lane] = h;
    }
}

// ---------------------------------------------------------------------------
extern "C" void kernel_launch(void* const* d_in, const int* in_sizes, int n_in,
                              void* d_out, int out_size, void* d_ws, size_t ws_size,
                              hipStream_t stream)
{
    const int*   seeds   = (const int*)d_in[0];
    const int*   neigh1  = (const int*)d_in[1];
    const int*   neigh2  = (const int*)d_in[2];
    const int*   ufi     = (const int*)d_in[3];
    const int*   ifi     = (const int*)d_in[4];
    const int*   uti     = (const int*)d_in[5];
    const int*   iti     = (const int*)d_in[6];
    const float* u_id    = (const float*)d_in[7];
    const float* i_id    = (const float*)d_in[8];
    const float* ufe     = (const float*)d_in[9];
    const float* ife     = (const float*)d_in[10];
    const float* wemb    = (const float*)d_in[11];
    const float* uw300   = (const float*)d_in[12];
    const float* iw300   = (const float*)d_in[13];
    const float* is768   = (const float*)d_in[14];
    const float* unum    = (const float*)d_in[15];
    const float* inum    = (const float*)d_in[16];
    const float* Wnum_u  = (const float*)d_in[17];
    const float* bnum_u  = (const float*)d_in[18];
    const float* Wnum_i  = (const float*)d_in[19];
    const float* bnum_i  = (const float*)d_in[20];
    const float* Wproj_u = (const float*)d_in[21];
    const float* bproj_u = (const float*)d_in[22];
    const float* Wproj_i = (const float*)d_in[23];
    const float* bproj_i = (const float*)d_in[24];
    const float* W_w     = (const float*)d_in[25];
    const float* b_w     = (const float*)d_in[26];
    const float* W_v     = (const float*)d_in[27];
    const float* b_v     = (const float*)d_in[28];

    // workspace: x[N_NODE*64] | h1[B*S*64] | h0[B*64]  (~49.4 MB)
    float* x  = (float*)d_ws;
    float* h1 = x  + (size_t)N_NODE * 64;
    float* h0 = h1 + (size_t)B_SEED * S_NB * 64;
    float* outp = (float*)d_out;

    proj_kernel<0><<<(N_USER + 63) / 64, 256, 0, stream>>>(
        u_id, ufi, ufe, uti, wemb, uw300, nullptr, unum,
        Wproj_u, bproj_u, Wnum_u, bnum_u, x, N_USER);
    proj_kernel<1><<<(M_ITEM + 63) / 64, 256, 0, stream>>>(
        i_id, ifi, ife, iti, wemb, iw300, is768, inum,
        Wproj_i, bproj_i, Wnum_i, bnum_i, x + (size_t)N_USER * 64, M_ITEM);

    // layer-0 on 1-hop nodes: h1[b,s]
    sage_kernel<1><<<(B_SEED * S_NB + 31) / 32, 256, 0, stream>>>(
        x, neigh1, x, neigh2, W_v, b_v, W_w, b_w, h1, B_SEED * S_NB);
    // layer-0 on seeds: h0[b]
    sage_kernel<1><<<(B_SEED + 31) / 32, 256, 0, stream>>>(
        x, seeds, x, neigh1, W_v, b_v, W_w, b_w, h0, B_SEED);
    // final layer (no relu): out[b]
    sage_kernel<0><<<(B_SEED + 31) / 32, 256, 0, stream>>>(
        h0, nullptr, h1, nullptr, W_v + 64 * 64, b_v + 64,
        W_w + 128 * 64, b_w + 64, outp, B_SEED);
}

// Round 2
// 709.419 us; speedup vs baseline: 12.7014x; 12.7014x over previous
//
#include <hip/hip_runtime.h>
#include <stdint.h>

#define N_USER 100000
#define M_ITEM 50000
#define N_NODE 150000
#define B_SEED 2048
#define S_NB 20

typedef __bf16 bf16x8 __attribute__((ext_vector_type(8)));
typedef float  f32x4  __attribute__((ext_vector_type(4)));

__device__ __forceinline__ uint16_t f2bf(float f) {
    uint32_t u = __float_as_uint(f);
    return (uint16_t)((u + 0x7FFFu + ((u >> 16) & 1u)) >> 16);   // RNE
}
__device__ __forceinline__ uint32_t pack2bf(float a, float b) {
    return (uint32_t)f2bf(a) | ((uint32_t)f2bf(b) << 16);
}

// ---------------------------------------------------------------------------
// WT prep: WT[d][k] = bf16( k<KPROJ ? Wproj[k][d] : (k<KTOT ? Wnum[k-KPROJ][d] : 0) )
// ---------------------------------------------------------------------------
__global__ void wtprep_kernel(const float* __restrict__ Wproj,
                              const float* __restrict__ Wnum,
                              uint16_t* __restrict__ WT,
                              int KPROJ, int KTOT, int KPAD)
{
    int idx = blockIdx.x * 256 + threadIdx.x;
    if (idx >= 64 * KPAD) return;
    int d = idx / KPAD, k = idx % KPAD;
    float v = 0.f;
    if (k < KPROJ)      v = Wproj[k * 64 + d];
    else if (k < KTOT)  v = Wnum[(k - KPROJ) * 64 + d];
    WT[(size_t)d * KPAD + k] = f2bf(v);
}

// ---------------------------------------------------------------------------
// Node-embedding projection via bf16 MFMA.
// Block: 256 thr / 4 waves, 64 nodes, all 64 output dims.
// Per 64-k chunk: stage A[64 nodes][64 k] (bf16, row stride 72 bf16 = 36 dw)
// into LDS via coalesced float2 gathers, then 2 MFMA k-steps x 4 d-blocks.
// K layout (users KTOT=534): [0,64) id | [64,128) feat | [128,224) text
//   | [224,524) word300 | [524,534) numeric
// items (KTOT=1302): ... | [524,1292) sent768 | [1292,1302) numeric
// ---------------------------------------------------------------------------
template<int IS_ITEM>
__global__ __launch_bounds__(256) void proj_mfma_kernel(
    const float* __restrict__ id_emb,
    const int*   __restrict__ feat_idx,
    const float* __restrict__ feat_emb,
    const int*   __restrict__ text_idx,
    const float* __restrict__ word_emb,
    const float* __restrict__ word300,
    const float* __restrict__ sent768,
    const float* __restrict__ numeric,
    const uint16_t* __restrict__ WT,
    const float* __restrict__ bproj,
    const float* __restrict__ bnum,
    float* __restrict__ xout,
    int ntype)
{
    constexpr int KPROJ = IS_ITEM ? 1292 : 524;
    constexpr int KTOT  = KPROJ + 10;
    constexpr int NCH   = (KTOT + 63) / 64;
    constexpr int KPAD  = NCH * 64;

    __shared__ uint32_t A_lds[64 * 36];   // 64 rows x 72 bf16 (4 bf16 pad/row)

    const int t   = threadIdx.x;
    const int w   = t >> 6;          // wave 0..3
    const int l   = t & 63;
    const int l15 = l & 15;
    const int g4  = l >> 4;          // 0..3
    const int nb  = blockIdx.x * 64;
    const int kp  = t & 31;          // k-pair within chunk
    const int ns  = t >> 5;          // node slot 0..7

    f32x4 acc[4] = {};               // d-blocks 0,16,32,48

    for (int c = 0; c < NCH; ++c) {
        const int k = c * 64 + 2 * kp;
        __syncthreads();
        // ---- stage: 8 iterations x (gather float2 -> bf16x2 -> LDS) ----
#pragma unroll 1
        for (int i = 0; i < 8; ++i) {
            const int n    = i * 8 + ns;
            const int node = nb + n;
            float v0 = 0.f, v1 = 0.f;
            if (node < ntype && k < KTOT) {
                if (k < 64) {
                    const float2 v = *(const float2*)(id_emb + (size_t)node * 64 + k);
                    v0 = v.x; v1 = v.y;
                } else if (k < 128) {
                    const int* fi = feat_idx + node * 10;
                    float s0 = 0.f, s1 = 0.f;
#pragma unroll
                    for (int j = 0; j < 10; ++j) {
                        const float2 e = *(const float2*)(feat_emb + (size_t)fi[j] * 64 + (k - 64));
                        s0 += e.x; s1 += e.y;
                    }
                    v0 = s0 * 0.1f; v1 = s1 * 0.1f;
                } else if (k < 224) {
                    const int kk2 = k - 128;
                    const int src = kk2 >> 5, wi = kk2 & 31;
                    const int* ti = text_idx + ((size_t)node * 3 + src) * 8;
                    float s0 = 0.f, s1 = 0.f;
#pragma unroll
                    for (int j = 0; j < 8; ++j) {
                        const float2 e = *(const float2*)(word_emb + (size_t)ti[j] * 32 + wi);
                        s0 += e.x; s1 += e.y;
                    }
                    v0 = s0 * 0.125f; v1 = s1 * 0.125f;
                } else if (k < 524) {
                    const float2 v = *(const float2*)(word300 + (size_t)node * 300 + (k - 224));
                    v0 = v.x; v1 = v.y;
                } else if (IS_ITEM && k < 1292) {
                    const float2 v = *(const float2*)(sent768 + (size_t)node * 768 + (k - 524));
                    v0 = v.x; v1 = v.y;
                } else {
                    const float2 v = *(const float2*)(numeric + (size_t)node * 10 + (k - KPROJ));
                    v0 = v.x; v1 = v.y;
                }
            }
            A_lds[n * 36 + kp] = pack2bf(v0, v1);
        }
        __syncthreads();
        // ---- compute: 2 k-steps of 32, 4 d-blocks ----
#pragma unroll
        for (int ks = 0; ks < 2; ++ks) {
            const bf16x8 af = *reinterpret_cast<const bf16x8*>(
                &A_lds[(w * 16 + l15) * 36 + ks * 16 + g4 * 4]);
#pragma unroll
            for (int db = 0; db < 4; ++db) {
                const bf16x8 bfg = *reinterpret_cast<const bf16x8*>(
                    WT + (size_t)(db * 16 + l15) * KPAD + c * 64 + ks * 32 + g4 * 8);
                acc[db] = __builtin_amdgcn_mfma_f32_16x16x32_bf16(af, bfg, acc[db], 0, 0, 0);
            }
        }
    }
    // ---- epilogue: D[node][d], col = l&15 = d-l15, row = g4*4+r = node ----
    const int node_base = nb + w * 16 + g4 * 4;
#pragma unroll
    for (int db = 0; db < 4; ++db) {
        const int d    = db * 16 + l15;
        const float bias = bproj[d] + bnum[d];
#pragma unroll
        for (int r = 0; r < 4; ++r) {
            const int node = node_base + r;
            if (node < ntype) xout[(size_t)node * 64 + d] = acc[db][r] + bias;
        }
    }
}

// ---------------------------------------------------------------------------
// Fused SAGE layer (fp32): per row r
//   m   = mean_j neigh_src[neigh_idx[r*S+j]]     (rows r*S+j if idx==NULL)
//   agg = m @ Wv + bv
//   h   = concat(self, agg) @ Ww + bw ; optional relu
// ---------------------------------------------------------------------------
template<int RELU>
__global__ __launch_bounds__(256) void sage_kernel(
    const float* __restrict__ self_src, const int* __restrict__ self_idx,
    const float* __restrict__ neigh_src, const int* __restrict__ neigh_idx,
    const float* __restrict__ Wv, const float* __restrict__ bv,
    const float* __restrict__ Ww, const float* __restrict__ bw,
    float* __restrict__ out, int nrows)
{
    __shared__ float WvL[64 * 64];
    __shared__ float WwL[128 * 64];
    const int t = threadIdx.x;
    for (int i = t; i < 64 * 64; i += 256)  WvL[i] = Wv[i];
    for (int i = t; i < 128 * 64; i += 256) WwL[i] = Ww[i];
    __syncthreads();

    const int wave = t >> 6, lane = t & 63;
    const int RPW  = 8;
    const int base = blockIdx.x * (4 * RPW) + wave * RPW;
    const float bvl = bv[lane], bwl = bw[lane];

    for (int i = 0; i < RPW; ++i) {
        const int r = base + i;
        if (r >= nrows) break;
        const int sidx = self_idx ? self_idx[r] : r;
        const float selfv = self_src[(size_t)sidx * 64 + lane];
        float mv = 0.f;
#pragma unroll
        for (int j = 0; j < S_NB; ++j) {
            const int nr = neigh_idx ? neigh_idx[r * S_NB + j] : (r * S_NB + j);
            mv += neigh_src[(size_t)nr * 64 + lane];
        }
        mv *= (1.f / S_NB);

        float agg = bvl;
#pragma unroll 8
        for (int kk = 0; kk < 64; ++kk)
            agg += __shfl(mv, kk) * WvL[kk * 64 + lane];

        float h = bwl;
#pragma unroll 8
        for (int kk = 0; kk < 64; ++kk)
            h += __shfl(selfv, kk) * WwL[kk * 64 + lane];
#pragma unroll 8
        for (int kk = 0; kk < 64; ++kk)
            h += __shfl(agg, kk) * WwL[(64 + kk) * 64 + lane];

        if (RELU) h = fmaxf(h, 0.f);
        out[(size_t)r * 64 + lane] = h;
    }
}

// ---------------------------------------------------------------------------
extern "C" void kernel_launch(void* const* d_in, const int* in_sizes, int n_in,
                              void* d_out, int out_size, void* d_ws, size_t ws_size,
                              hipStream_t stream)
{
    const int*   seeds   = (const int*)d_in[0];
    const int*   neigh1  = (const int*)d_in[1];
    const int*   neigh2  = (const int*)d_in[2];
    const int*   ufi     = (const int*)d_in[3];
    const int*   ifi     = (const int*)d_in[4];
    const int*   uti     = (const int*)d_in[5];
    const int*   iti     = (const int*)d_in[6];
    const float* u_id    = (const float*)d_in[7];
    const float* i_id    = (const float*)d_in[8];
    const float* ufe     = (const float*)d_in[9];
    const float* ife     = (const float*)d_in[10];
    const float* wemb    = (const float*)d_in[11];
    const float* uw300   = (const float*)d_in[12];
    const float* iw300   = (const float*)d_in[13];
    const float* is768   = (const float*)d_in[14];
    const float* unum    = (const float*)d_in[15];
    const float* inum    = (const float*)d_in[16];
    const float* Wnum_u  = (const float*)d_in[17];
    const float* bnum_u  = (const float*)d_in[18];
    const float* Wnum_i  = (const float*)d_in[19];
    const float* bnum_i  = (const float*)d_in[20];
    const float* Wproj_u = (const float*)d_in[21];
    const float* bproj_u = (const float*)d_in[22];
    const float* Wproj_i = (const float*)d_in[23];
    const float* bproj_i = (const float*)d_in[24];
    const float* W_w     = (const float*)d_in[25];
    const float* b_w     = (const float*)d_in[26];
    const float* W_v     = (const float*)d_in[27];
    const float* b_v     = (const float*)d_in[28];

    const int KPAD_U = 576, KPAD_I = 1344;

    // ws layout: WTU | WTI | x | h1 | h0
    uint16_t* WTU = (uint16_t*)d_ws;
    uint16_t* WTI = WTU + (size_t)64 * KPAD_U;
    float* x  = (float*)(WTI + (size_t)64 * KPAD_I);
    float* h1 = x  + (size_t)N_NODE * 64;
    float* h0 = h1 + (size_t)B_SEED * S_NB * 64;
    float* outp = (float*)d_out;

    wtprep_kernel<<<(64 * KPAD_U + 255) / 256, 256, 0, stream>>>(
        Wproj_u, Wnum_u, WTU, 524, 534, KPAD_U);
    wtprep_kernel<<<(64 * KPAD_I + 255) / 256, 256, 0, stream>>>(
        Wproj_i, Wnum_i, WTI, 1292, 1302, KPAD_I);

    proj_mfma_kernel<0><<<(N_USER + 63) / 64, 256, 0, stream>>>(
        u_id, ufi, ufe, uti, wemb, uw300, nullptr, unum,
        WTU, bproj_u, bnum_u, x, N_USER);
    proj_mfma_kernel<1><<<(M_ITEM + 63) / 64, 256, 0, stream>>>(
        i_id, ifi, ife, iti, wemb, iw300, is768, inum,
        WTI, bproj_i, bnum_i, x + (size_t)N_USER * 64, M_ITEM);

    sage_kernel<1><<<(B_SEED * S_NB + 31) / 32, 256, 0, stream>>>(
        x, neigh1, x, neigh2, W_v, b_v, W_w, b_w, h1, B_SEED * S_NB);
    sage_kernel<1><<<(B_SEED + 31) / 32, 256, 0, stream>>>(
        x, seeds, x, neigh1, W_v, b_v, W_w, b_w, h0, B_SEED);
    sage_kernel<0><<<(B_SEED + 31) / 32, 256, 0, stream>>>(
        h0, nullptr, h1, nullptr, W_v + 64 * 64, b_v + 64,
        W_w + 128 * 64, b_w + 64, outp, B_SEED);
}

// Round 3
// 485.654 us; speedup vs baseline: 18.5536x; 1.4608x over previous
//
#include <hip/hip_runtime.h>
#include <stdint.h>

#define N_USER 100000
#define M_ITEM 50000
#define N_NODE 150000
#define B_SEED 2048
#define S_NB 20

typedef __bf16   bf16x8 __attribute__((ext_vector_type(8)));
typedef float    f32x4  __attribute__((ext_vector_type(4)));
typedef uint32_t u32x4  __attribute__((ext_vector_type(4)));

__device__ __forceinline__ uint16_t f2bf(float f) {
    uint32_t u = __float_as_uint(f);
    return (uint16_t)((u + 0x7FFFu + ((u >> 16) & 1u)) >> 16);   // RNE
}
__device__ __forceinline__ uint32_t pack2bf(float a, float b) {
    return (uint32_t)f2bf(a) | ((uint32_t)f2bf(b) << 16);
}
__device__ __forceinline__ float bf2f(uint16_t u) {
    return __uint_as_float(((uint32_t)u) << 16);
}

union BF8 { bf16x8 v; uint32_t u[4]; };

__device__ __forceinline__ bf16x8 ldf32x8(const float* p, bool valid) {
    BF8 r;
    if (valid) {
        const float4 a = *(const float4*)p, b = *(const float4*)(p + 4);
        r.u[0] = pack2bf(a.x, a.y); r.u[1] = pack2bf(a.z, a.w);
        r.u[2] = pack2bf(b.x, b.y); r.u[3] = pack2bf(b.z, b.w);
    } else { r.u[0] = r.u[1] = r.u[2] = r.u[3] = 0; }
    return r.v;
}
__device__ __forceinline__ bf16x8 ldf32x8_mask(const float* rowp, int base, int limit, bool valid) {
    BF8 r;
#pragma unroll
    for (int h = 0; h < 4; ++h) {
        const int k0 = base + 2 * h;
        const float a = (valid && k0     < limit) ? rowp[k0]     : 0.f;
        const float b = (valid && k0 + 1 < limit) ? rowp[k0 + 1] : 0.f;
        r.u[h] = pack2bf(a, b);
    }
    return r.v;
}

// ---------------------------------------------------------------------------
// WT prep with permuted K order:
//   k' [0,160)    -> orig k = 64+k'   (feat 64 | text 96, the LDS-gathered block)
//   k' [160,224)  -> orig k = k'-160  (id emb)
//   k' [224,256)  -> numeric j=k'-224 (10 valid, rest 0)
//   k' [256,576)  -> word300 j=k'-256 (300 valid, rest 0)
//   k' [576,1344) -> sent768 j=k'-576 (items only)
// ---------------------------------------------------------------------------
__global__ void wtprep_kernel(const float* __restrict__ Wproj,
                              const float* __restrict__ Wnum,
                              uint16_t* __restrict__ WT, int KPADP)
{
    const int idx = blockIdx.x * 256 + threadIdx.x;   // grid sized exactly
    const int d = idx / KPADP, kp = idx - d * KPADP;
    float v = 0.f;
    if (kp < 160)      v = Wproj[(64 + kp) * 64 + d];
    else if (kp < 224) v = Wproj[(kp - 160) * 64 + d];
    else if (kp < 256) { const int j = kp - 224; if (j < 10)  v = Wnum[j * 64 + d]; }
    else if (kp < 576) { const int j = kp - 256; if (j < 300) v = Wproj[(224 + j) * 64 + d]; }
    else               { const int j = kp - 576; v = Wproj[(524 + j) * 64 + d]; }
    WT[(size_t)d * KPADP + kp] = f2bf(v);
}

// WvT0[d][k] = Wv0[k][d]; WwT0[d][k] = Ww0[k][d]  (bf16)
__global__ void smallprep_kernel(const float* __restrict__ Wv0, const float* __restrict__ Ww0,
                                 uint16_t* __restrict__ WvT, uint16_t* __restrict__ WwT)
{
    const int idx = blockIdx.x * 256 + threadIdx.x;   // 12288 total
    if (idx < 4096) {
        const int d = idx >> 6, k = idx & 63;
        WvT[d * 64 + k] = f2bf(Wv0[k * 64 + d]);
    } else {
        const int i2 = idx - 4096;
        const int d = i2 >> 7, k = i2 & 127;
        WwT[d * 128 + k] = f2bf(Ww0[k * 64 + d]);
    }
}

// ---------------------------------------------------------------------------
// Projection: x[node] = A[node] @ WT^T + bias   (K-permuted, bf16 MFMA)
// Phase 1 (one barrier): gather feat-mean + text-mean -> LDS G[64][160] bf16.
// Phase 2: 18 (users) / 42 (items) k-steps; gathered seg from LDS, dense segs
// directly global->fragment. Output x in bf16.
// ---------------------------------------------------------------------------
template<int IS_ITEM>
__global__ __launch_bounds__(256) void proj_kernel(
    const float* __restrict__ id_emb,
    const int*   __restrict__ feat_idx,
    const float* __restrict__ feat_emb,
    const int*   __restrict__ text_idx,
    const float* __restrict__ word_emb,
    const float* __restrict__ word300,
    const float* __restrict__ sent768,
    const float* __restrict__ numeric,
    const uint16_t* __restrict__ WT,
    const float* __restrict__ bproj,
    const float* __restrict__ bnum,
    uint16_t* __restrict__ xout,
    int ntype)
{
    constexpr int KPADP = IS_ITEM ? 1344 : 576;
    __shared__ uint32_t G[64 * 92];   // 64 nodes x 160 bf16 (stride 92 dw)

    const int t = threadIdx.x;
    const int w = t >> 6, l = t & 63;
    const int l15 = l & 15, g4 = l >> 4;
    const int nb = blockIdx.x * 64;

    // ---- phase 1: gathered dims (feat 64 | text 96) ----
#pragma unroll 1
    for (int it = 0; it < 20; ++it) {
        const int task = t + it * 256;            // 0..5119
        const int n = task / 80, p = task - n * 80;
        const int node = nb + n;
        float v0 = 0.f, v1 = 0.f;
        if (node < ntype) {
            if (p < 32) {
                const int* fi = feat_idx + (size_t)node * 10;
                float s0 = 0.f, s1 = 0.f;
#pragma unroll
                for (int j = 0; j < 10; ++j) {
                    const float2 e = *(const float2*)(feat_emb + (size_t)fi[j] * 64 + 2 * p);
                    s0 += e.x; s1 += e.y;
                }
                v0 = s0 * 0.1f; v1 = s1 * 0.1f;
            } else {
                const int q = p - 32, src = q >> 4, wp = q & 15;
                const int* ti = text_idx + ((size_t)node * 3 + src) * 8;
                float s0 = 0.f, s1 = 0.f;
#pragma unroll
                for (int j = 0; j < 8; ++j) {
                    const float2 e = *(const float2*)(word_emb + (size_t)ti[j] * 32 + 2 * wp);
                    s0 += e.x; s1 += e.y;
                }
                v0 = s0 * 0.125f; v1 = s1 * 0.125f;
            }
        }
        G[n * 92 + p] = pack2bf(v0, v1);
    }
    __syncthreads();

    // ---- phase 2: MFMA over permuted K ----
    const int row  = w * 16 + l15;
    const int node = nb + row;
    const bool valid = node < ntype;

    f32x4 acc[4] = {};
    const uint16_t* WTb = WT + (size_t)l15 * KPADP + g4 * 8;

    auto MM = [&](bf16x8 af, int kb) {
#pragma unroll
        for (int db = 0; db < 4; ++db) {
            const bf16x8 bfr = *reinterpret_cast<const bf16x8*>(WTb + (size_t)db * 16 * KPADP + kb);
            acc[db] = __builtin_amdgcn_mfma_f32_16x16x32_bf16(af, bfr, acc[db], 0, 0, 0);
        }
    };

    // seg0: gathered (LDS), k' 0..160
#pragma unroll
    for (int ks = 0; ks < 5; ++ks) {
        const bf16x8 af = *reinterpret_cast<const bf16x8*>(&G[row * 92 + ks * 16 + g4 * 4]);
        MM(af, ks * 32);
    }
    // seg1: id emb, k' 160..224
    const float* idr = id_emb + (size_t)node * 64;
#pragma unroll
    for (int ks = 0; ks < 2; ++ks)
        MM(ldf32x8(idr + ks * 32 + g4 * 8, valid), 160 + ks * 32);
    // seg2: numeric (10 valid), k' 224..256
    MM(ldf32x8_mask(numeric + (size_t)node * 10, g4 * 8, 10, valid), 224);
    // seg3: word300, k' 256..576 (9 full + 1 masked)
    const float* wr = word300 + (size_t)node * 300;
#pragma unroll 1
    for (int ks = 0; ks < 9; ++ks)
        MM(ldf32x8(wr + ks * 32 + g4 * 8, valid), 256 + ks * 32);
    MM(ldf32x8_mask(wr, 288 + g4 * 8, 300, valid), 256 + 288);
    // seg4: sent768 (items), k' 576..1344
    if (IS_ITEM) {
        const float* sr = sent768 + (size_t)node * 768;
#pragma unroll 1
        for (int ks = 0; ks < 24; ++ks)
            MM(ldf32x8(sr + ks * 32 + g4 * 8, valid), 576 + ks * 32);
    }

    // ---- epilogue: row = g4*4+r, col d = db*16+l15 ----
    const int node_base = nb + w * 16 + g4 * 4;
#pragma unroll
    for (int db = 0; db < 4; ++db) {
        const int d = db * 16 + l15;
        const float bias = bproj[d] + bnum[d];
#pragma unroll
        for (int r = 0; r < 4; ++r) {
            const int nn = node_base + r;
            if (nn < ntype) xout[(size_t)nn * 64 + d] = f2bf(acc[db][r] + bias);
        }
    }
}

// ---------------------------------------------------------------------------
// xv = x @ Wv0 + bv0   (bf16 in/out, per node)
// ---------------------------------------------------------------------------
__global__ __launch_bounds__(256) void xv_kernel(
    const uint16_t* __restrict__ x, const uint16_t* __restrict__ WvT,
    const float* __restrict__ bv, uint16_t* __restrict__ xv, int n)
{
    const int t = threadIdx.x;
    const int w = t >> 6, l = t & 63, l15 = l & 15, g4 = l >> 4;
    const int node = blockIdx.x * 64 + w * 16 + l15;
    const bool valid = node < n;

    f32x4 acc[4] = {};
    const uint16_t* WTb = WvT + l15 * 64 + g4 * 8;
#pragma unroll
    for (int ks = 0; ks < 2; ++ks) {
        bf16x8 af;
        if (valid) af = *reinterpret_cast<const bf16x8*>(x + (size_t)node * 64 + ks * 32 + g4 * 8);
        else { BF8 z; z.u[0]=z.u[1]=z.u[2]=z.u[3]=0; af = z.v; }
#pragma unroll
        for (int db = 0; db < 4; ++db) {
            const bf16x8 bfr = *reinterpret_cast<const bf16x8*>(WTb + db * 16 * 64 + ks * 32);
            acc[db] = __builtin_amdgcn_mfma_f32_16x16x32_bf16(af, bfr, acc[db], 0, 0, 0);
        }
    }
    const int node_base = blockIdx.x * 64 + w * 16 + g4 * 4;
#pragma unroll
    for (int db = 0; db < 4; ++db) {
        const int d = db * 16 + l15;
        const float bias = bv[d];
#pragma unroll
        for (int r = 0; r < 4; ++r) {
            const int nn = node_base + r;
            if (nn < n) xv[(size_t)nn * 64 + d] = f2bf(acc[db][r] + bias);
        }
    }
}

// ---------------------------------------------------------------------------
// SAGE layer-0 (MFMA): out[r] = act( [ x[self[r]] | mean_j xv[neigh[r,j]] ] @ Ww0 + bw0 )
// nrows must be a multiple of 64.
// ---------------------------------------------------------------------------
__global__ __launch_bounds__(256) void sage_mfma_kernel(
    const uint16_t* __restrict__ x, const uint16_t* __restrict__ xv,
    const int* __restrict__ self_idx, const int* __restrict__ neigh_idx,
    const uint16_t* __restrict__ WwT, const float* __restrict__ bw,
    uint16_t* __restrict__ out, int relu)
{
    const int t = threadIdx.x;
    const int w = t >> 6, l = t & 63, l15 = l & 15, g4 = l >> 4;
    const int r = blockIdx.x * 64 + w * 16 + l15;
    const int sidx = self_idx[r];
    const int* ni = neigh_idx + (size_t)r * S_NB;

    f32x4 acc[4] = {};
    const uint16_t* WTb = WwT + l15 * 128 + g4 * 8;

    auto MM = [&](bf16x8 af, int kb) {
#pragma unroll
        for (int db = 0; db < 4; ++db) {
            const bf16x8 bfr = *reinterpret_cast<const bf16x8*>(WTb + db * 16 * 128 + kb);
            acc[db] = __builtin_amdgcn_mfma_f32_16x16x32_bf16(af, bfr, acc[db], 0, 0, 0);
        }
    };

    // self segment k' 0..64
#pragma unroll
    for (int ks = 0; ks < 2; ++ks) {
        const bf16x8 af = *reinterpret_cast<const bf16x8*>(x + (size_t)sidx * 64 + ks * 32 + g4 * 8);
        MM(af, ks * 32);
    }
    // agg segment k' 64..128: fp32 mean of 20 bf16x8 rows of xv
#pragma unroll
    for (int ks = 0; ks < 2; ++ks) {
        float ev[4] = {0.f, 0.f, 0.f, 0.f}, od[4] = {0.f, 0.f, 0.f, 0.f};
#pragma unroll
        for (int j = 0; j < S_NB; ++j) {
            const u32x4 v = *reinterpret_cast<const u32x4*>(xv + (size_t)ni[j] * 64 + ks * 32 + g4 * 8);
#pragma unroll
            for (int q = 0; q < 4; ++q) {
                ev[q] += __uint_as_float(v[q] << 16);
                od[q] += __uint_as_float(v[q] & 0xffff0000u);
            }
        }
        BF8 m;
#pragma unroll
        for (int q = 0; q < 4; ++q) m.u[q] = pack2bf(ev[q] * (1.f / S_NB), od[q] * (1.f / S_NB));
        MM(m.v, 64 + ks * 32);
    }

    const int rb = blockIdx.x * 64 + w * 16 + g4 * 4;
#pragma unroll
    for (int db = 0; db < 4; ++db) {
        const int d = db * 16 + l15;
        const float bias = bw[d];
#pragma unroll
        for (int rr = 0; rr < 4; ++rr) {
            float h = acc[db][rr] + bias;
            if (relu) h = fmaxf(h, 0.f);
            out[(size_t)(rb + rr) * 64 + d] = f2bf(h);
        }
    }
}

// ---------------------------------------------------------------------------
// Final layer (fp32 shfl GEMV, 2048 rows):
// out[b] = [ h0[b] | (mean_s h1[b,s]) @ Wv1 + bv1 ] @ Ww1 + bw1
// ---------------------------------------------------------------------------
__global__ __launch_bounds__(256) void final_kernel(
    const uint16_t* __restrict__ h0, const uint16_t* __restrict__ h1,
    const float* __restrict__ Wv, const float* __restrict__ bv,
    const float* __restrict__ Ww, const float* __restrict__ bw,
    float* __restrict__ out)
{
    __shared__ float WvL[64 * 64];
    __shared__ float WwL[128 * 64];
    const int t = threadIdx.x;
    for (int i = t; i < 64 * 64; i += 256)  WvL[i] = Wv[i];
    for (int i = t; i < 128 * 64; i += 256) WwL[i] = Ww[i];
    __syncthreads();

    const int wave = t >> 6, lane = t & 63;
    const int base = blockIdx.x * 32 + wave * 8;
    const float bvl = bv[lane], bwl = bw[lane];

    for (int i = 0; i < 8; ++i) {
        const int b = base + i;
        float m = 0.f;
#pragma unroll
        for (int s = 0; s < S_NB; ++s)
            m += bf2f(h1[(size_t)(b * S_NB + s) * 64 + lane]);
        m *= (1.f / S_NB);

        float agg = bvl;
#pragma unroll 8
        for (int k = 0; k < 64; ++k)
            agg += __shfl(m, k) * WvL[k * 64 + lane];

        const float selfv = bf2f(h0[(size_t)b * 64 + lane]);
        float h = bwl;
#pragma unroll 8
        for (int k = 0; k < 64; ++k)
            h += __shfl(selfv, k) * WwL[k * 64 + lane];
#pragma unroll 8
        for (int k = 0; k < 64; ++k)
            h += __shfl(agg, k) * WwL[(64 + k) * 64 + lane];

        out[(size_t)b * 64 + lane] = h;
    }
}

// ---------------------------------------------------------------------------
extern "C" void kernel_launch(void* const* d_in, const int* in_sizes, int n_in,
                              void* d_out, int out_size, void* d_ws, size_t ws_size,
                              hipStream_t stream)
{
    const int*   seeds   = (const int*)d_in[0];
    const int*   neigh1  = (const int*)d_in[1];
    const int*   neigh2  = (const int*)d_in[2];
    const int*   ufi     = (const int*)d_in[3];
    const int*   ifi     = (const int*)d_in[4];
    const int*   uti     = (const int*)d_in[5];
    const int*   iti     = (const int*)d_in[6];
    const float* u_id    = (const float*)d_in[7];
    const float* i_id    = (const float*)d_in[8];
    const float* ufe     = (const float*)d_in[9];
    const float* ife     = (const float*)d_in[10];
    const float* wemb    = (const float*)d_in[11];
    const float* uw300   = (const float*)d_in[12];
    const float* iw300   = (const float*)d_in[13];
    const float* is768   = (const float*)d_in[14];
    const float* unum    = (const float*)d_in[15];
    const float* inum    = (const float*)d_in[16];
    const float* Wnum_u  = (const float*)d_in[17];
    const float* bnum_u  = (const float*)d_in[18];
    const float* Wnum_i  = (const float*)d_in[19];
    const float* bnum_i  = (const float*)d_in[20];
    const float* Wproj_u = (const float*)d_in[21];
    const float* bproj_u = (const float*)d_in[22];
    const float* Wproj_i = (const float*)d_in[23];
    const float* bproj_i = (const float*)d_in[24];
    const float* W_w     = (const float*)d_in[25];
    const float* b_w     = (const float*)d_in[26];
    const float* W_v     = (const float*)d_in[27];
    const float* b_v     = (const float*)d_in[28];

    // ws layout (uint16 elements)
    uint16_t* WTU  = (uint16_t*)d_ws;                       // 64*576
    uint16_t* WTI  = WTU  + 36864;                          // 64*1344
    uint16_t* WvT0 = WTI  + 86016;                          // 64*64
    uint16_t* WwT0 = WvT0 + 4096;                           // 64*128
    uint16_t* xbf  = WwT0 + 8192;                           // N_NODE*64
    uint16_t* xvbf = xbf  + (size_t)N_NODE * 64;            // N_NODE*64
    uint16_t* h1bf = xvbf + (size_t)N_NODE * 64;            // 40960*64
    uint16_t* h0bf = h1bf + (size_t)B_SEED * S_NB * 64;     // 2048*64
    float* outp = (float*)d_out;

    wtprep_kernel<<<144, 256, 0, stream>>>(Wproj_u, Wnum_u, WTU, 576);
    wtprep_kernel<<<336, 256, 0, stream>>>(Wproj_i, Wnum_i, WTI, 1344);
    smallprep_kernel<<<48, 256, 0, stream>>>(W_v, W_w, WvT0, WwT0);

    proj_kernel<0><<<(N_USER + 63) / 64, 256, 0, stream>>>(
        u_id, ufi, ufe, uti, wemb, uw300, nullptr, unum,
        WTU, bproj_u, bnum_u, xbf, N_USER);
    proj_kernel<1><<<(M_ITEM + 63) / 64, 256, 0, stream>>>(
        i_id, ifi, ife, iti, wemb, iw300, is768, inum,
        WTI, bproj_i, bnum_i, xbf + (size_t)N_USER * 64, M_ITEM);

    xv_kernel<<<(N_NODE + 63) / 64, 256, 0, stream>>>(xbf, WvT0, b_v, xvbf, N_NODE);

    sage_mfma_kernel<<<(B_SEED * S_NB) / 64, 256, 0, stream>>>(
        xbf, xvbf, neigh1, neigh2, WwT0, b_w, h1bf, 1);
    sage_mfma_kernel<<<B_SEED / 64, 256, 0, stream>>>(
        xbf, xvbf, seeds, neigh1, WwT0, b_w, h0bf, 1);

    final_kernel<<<B_SEED / 32, 256, 0, stream>>>(
        h0bf, h1bf, W_v + 4096, b_v + 64, W_w + 8192, b_w + 64, outp);
}

// Round 4
// 438.768 us; speedup vs baseline: 20.5361x; 1.1069x over previous
//
#include <hip/hip_runtime.h>
#include <stdint.h>

#define N_USER 100000
#define M_ITEM 50000
#define N_NODE 150000
#define B_SEED 2048
#define S_NB 20

typedef __bf16   bf16x8 __attribute__((ext_vector_type(8)));
typedef float    f32x4  __attribute__((ext_vector_type(4)));
typedef uint32_t u32x4  __attribute__((ext_vector_type(4)));

__device__ __forceinline__ uint16_t f2bf(float f) {
    uint32_t u = __float_as_uint(f);
    return (uint16_t)((u + 0x7FFFu + ((u >> 16) & 1u)) >> 16);   // RNE
}
__device__ __forceinline__ uint32_t pack2bf(float a, float b) {
    return (uint32_t)f2bf(a) | ((uint32_t)f2bf(b) << 16);
}
__device__ __forceinline__ float bf2f(uint16_t u) {
    return __uint_as_float(((uint32_t)u) << 16);
}

union BF8 { bf16x8 v; uint32_t u[4]; };

__device__ __forceinline__ bf16x8 pack8(const float4 lo, const float4 hi) {
    BF8 r;
    r.u[0] = pack2bf(lo.x, lo.y); r.u[1] = pack2bf(lo.z, lo.w);
    r.u[2] = pack2bf(hi.x, hi.y); r.u[3] = pack2bf(hi.z, hi.w);
    return r.v;
}
// exact masked fragment (for K-tails where W is nonzero and placement matters)
__device__ __forceinline__ bf16x8 ldf32x8_mask(const float* rowp, int base, int limit) {
    BF8 r;
#pragma unroll
    for (int h = 0; h < 4; ++h) {
        const int k0 = base + 2 * h;
        const float a = (k0     < limit) ? rowp[k0]     : 0.f;
        const float b = (k0 + 1 < limit) ? rowp[k0 + 1] : 0.f;
        r.u[h] = pack2bf(a, b);
    }
    return r.v;
}

// ---------------------------------------------------------------------------
// WT prep with permuted K order:
//   k' [0,64)     -> feat dims     (orig k = 64+k')
//   k' [64,160)   -> text dims     (orig k = 64+k')
//   k' [160,224)  -> id emb        (orig k = k'-160)
//   k' [224,256)  -> numeric j=k'-224 (10 valid, rest 0)
//   k' [256,576)  -> word300 j=k'-256 (300 valid, rest 0)
//   k' [576,1344) -> sent768 j=k'-576 (items only)
// ---------------------------------------------------------------------------
__global__ void wtprep_kernel(const float* __restrict__ Wproj,
                              const float* __restrict__ Wnum,
                              uint16_t* __restrict__ WT, int KPADP)
{
    const int idx = blockIdx.x * 256 + threadIdx.x;   // grid sized exactly
    const int d = idx / KPADP, kp = idx - d * KPADP;
    float v = 0.f;
    if (kp < 160)      v = Wproj[(64 + kp) * 64 + d];
    else if (kp < 224) v = Wproj[(kp - 160) * 64 + d];
    else if (kp < 256) { const int j = kp - 224; if (j < 10)  v = Wnum[j * 64 + d]; }
    else if (kp < 576) { const int j = kp - 256; if (j < 300) v = Wproj[(224 + j) * 64 + d]; }
    else               { const int j = kp - 576; v = Wproj[(524 + j) * 64 + d]; }
    WT[(size_t)d * KPADP + kp] = f2bf(v);
}

// WvT0[d][k] = Wv0[k][d]; WwT0[d][k] = Ww0[k][d]  (bf16)
__global__ void smallprep_kernel(const float* __restrict__ Wv0, const float* __restrict__ Ww0,
                                 uint16_t* __restrict__ WvT, uint16_t* __restrict__ WwT)
{
    const int idx = blockIdx.x * 256 + threadIdx.x;   // 12288 total
    if (idx < 4096) {
        const int d = idx >> 6, k = idx & 63;
        WvT[d * 64 + k] = f2bf(Wv0[k * 64 + d]);
    } else {
        const int i2 = idx - 4096;
        const int d = i2 >> 7, k = i2 & 127;
        WwT[d * 128 + k] = f2bf(Ww0[k * 64 + d]);
    }
}

// ---------------------------------------------------------------------------
// Projection, LDS-free: every A-fragment (incl. gathered feat/text means) is
// built directly in registers by the consuming lane (l15 = node-in-16,
// g4 = k-octet). No barriers; dense segments batched for load ILP.
// ---------------------------------------------------------------------------
template<int IS_ITEM>
__global__ __launch_bounds__(256, 4) void proj_kernel(
    const float* __restrict__ id_emb,
    const int*   __restrict__ feat_idx,
    const float* __restrict__ feat_emb,
    const int*   __restrict__ text_idx,
    const float* __restrict__ word_emb,
    const float* __restrict__ word300,
    const float* __restrict__ sent768,
    const float* __restrict__ numeric,
    const uint16_t* __restrict__ WT,
    const float* __restrict__ bproj,
    const float* __restrict__ bnum,
    uint16_t* __restrict__ xout,
    int ntype)
{
    constexpr int KPADP = IS_ITEM ? 1344 : 576;

    const int t = threadIdx.x;
    const int w = t >> 6, l = t & 63;
    const int l15 = l & 15, g4 = l >> 4;
    const int nb = blockIdx.x * 64;
    const int node = nb + w * 16 + l15;
    const int node_c = node < ntype ? node : ntype - 1;   // clamp for addressing

    f32x4 acc[4] = {};
    const uint16_t* WTb = WT + (size_t)l15 * KPADP + g4 * 8;

    auto MM = [&](bf16x8 af, int kb) {
#pragma unroll
        for (int db = 0; db < 4; ++db) {
            const bf16x8 bfr = *reinterpret_cast<const bf16x8*>(WTb + (size_t)db * 16 * KPADP + kb);
            acc[db] = __builtin_amdgcn_mfma_f32_16x16x32_bf16(af, bfr, acc[db], 0, 0, 0);
        }
    };

    // ---- feat segment k' [0,64): mean of 10 feat_emb rows ----
    {
        const int* fip = feat_idx + (size_t)node_c * 10;
        int fi[10];
#pragma unroll
        for (int j = 0; j < 10; ++j) fi[j] = fip[j];
#pragma unroll
        for (int ks = 0; ks < 2; ++ks) {
            float4 s0 = make_float4(0.f, 0.f, 0.f, 0.f);
            float4 s1 = make_float4(0.f, 0.f, 0.f, 0.f);
#pragma unroll
            for (int j = 0; j < 10; ++j) {
                const float* rp = feat_emb + (size_t)fi[j] * 64 + ks * 32 + g4 * 8;
                const float4 a = *(const float4*)rp;
                const float4 b = *(const float4*)(rp + 4);
                s0.x += a.x; s0.y += a.y; s0.z += a.z; s0.w += a.w;
                s1.x += b.x; s1.y += b.y; s1.z += b.z; s1.w += b.w;
            }
            MM(pack8(make_float4(s0.x * 0.1f, s0.y * 0.1f, s0.z * 0.1f, s0.w * 0.1f),
                     make_float4(s1.x * 0.1f, s1.y * 0.1f, s1.z * 0.1f, s1.w * 0.1f)),
               ks * 32);
        }
    }

    // ---- text segment k' [64,160): 3 sources x mean of 8 word_emb rows ----
#pragma unroll
    for (int src = 0; src < 3; ++src) {
        const int* tip = text_idx + ((size_t)node_c * 3 + src) * 8;
        int tok[8];
#pragma unroll
        for (int j = 0; j < 8; ++j) tok[j] = tip[j];
        float4 s0 = make_float4(0.f, 0.f, 0.f, 0.f);
        float4 s1 = make_float4(0.f, 0.f, 0.f, 0.f);
#pragma unroll
        for (int j = 0; j < 8; ++j) {
            const float* rp = word_emb + (size_t)tok[j] * 32 + g4 * 8;
            const float4 a = *(const float4*)rp;
            const float4 b = *(const float4*)(rp + 4);
            s0.x += a.x; s0.y += a.y; s0.z += a.z; s0.w += a.w;
            s1.x += b.x; s1.y += b.y; s1.z += b.z; s1.w += b.w;
        }
        MM(pack8(make_float4(s0.x * 0.125f, s0.y * 0.125f, s0.z * 0.125f, s0.w * 0.125f),
                 make_float4(s1.x * 0.125f, s1.y * 0.125f, s1.z * 0.125f, s1.w * 0.125f)),
           64 + src * 32);
    }

    // ---- id segment k' [160,224) ----
    {
        const float* idr = id_emb + (size_t)node_c * 64;
#pragma unroll
        for (int ks = 0; ks < 2; ++ks) {
            const float* p = idr + ks * 32 + g4 * 8;
            MM(pack8(*(const float4*)p, *(const float4*)(p + 4)), 160 + ks * 32);
        }
    }

    // ---- numeric k' [224,256): 10 valid, exact mask ----
    MM(ldf32x8_mask(numeric + (size_t)node_c * 10, g4 * 8, 10), 224);

    // ---- word300 k' [256,576): 9 full k-steps + 1 masked, batched 5 ----
    {
        const float* wr = word300 + (size_t)node_c * 300;
#pragma unroll
        for (int b = 0; b < 2; ++b) {
            float4 va[5][2];
#pragma unroll
            for (int u = 0; u < 5; ++u) {
                const int ks = b * 5 + u;
                if (ks < 9) {
                    const float* p = wr + ks * 32 + g4 * 8;
                    va[u][0] = *(const float4*)p;
                    va[u][1] = *(const float4*)(p + 4);
                }
            }
#pragma unroll
            for (int u = 0; u < 5; ++u) {
                const int ks = b * 5 + u;
                const bf16x8 af = (ks < 9) ? pack8(va[u][0], va[u][1])
                                           : ldf32x8_mask(wr, 288 + g4 * 8, 300);
                MM(af, 256 + ks * 32);
            }
        }
    }

    // ---- sent768 k' [576,1344): items only, 24 k-steps batched 6 ----
    if (IS_ITEM) {
        const float* sr = sent768 + (size_t)node_c * 768;
#pragma unroll
        for (int b = 0; b < 4; ++b) {
            float4 va[6][2];
#pragma unroll
            for (int u = 0; u < 6; ++u) {
                const float* p = sr + (b * 6 + u) * 32 + g4 * 8;
                va[u][0] = *(const float4*)p;
                va[u][1] = *(const float4*)(p + 4);
            }
#pragma unroll
            for (int u = 0; u < 6; ++u)
                MM(pack8(va[u][0], va[u][1]), 576 + (b * 6 + u) * 32);
        }
    }

    // ---- epilogue: D row = g4*4+r (node), col d = db*16+l15 ----
    const int node_base = nb + w * 16 + g4 * 4;
#pragma unroll
    for (int db = 0; db < 4; ++db) {
        const int d = db * 16 + l15;
        const float bias = bproj[d] + bnum[d];
#pragma unroll
        for (int r = 0; r < 4; ++r) {
            const int nn = node_base + r;
            if (nn < ntype) xout[(size_t)nn * 64 + d] = f2bf(acc[db][r] + bias);
        }
    }
}

// ---------------------------------------------------------------------------
// xv = x @ Wv0 + bv0   (bf16 in/out, per node)
// ---------------------------------------------------------------------------
__global__ __launch_bounds__(256) void xv_kernel(
    const uint16_t* __restrict__ x, const uint16_t* __restrict__ WvT,
    const float* __restrict__ bv, uint16_t* __restrict__ xv, int n)
{
    const int t = threadIdx.x;
    const int w = t >> 6, l = t & 63, l15 = l & 15, g4 = l >> 4;
    const int node = blockIdx.x * 64 + w * 16 + l15;
    const int node_c = node < n ? node : n - 1;

    f32x4 acc[4] = {};
    const uint16_t* WTb = WvT + l15 * 64 + g4 * 8;
#pragma unroll
    for (int ks = 0; ks < 2; ++ks) {
        const bf16x8 af = *reinterpret_cast<const bf16x8*>(x + (size_t)node_c * 64 + ks * 32 + g4 * 8);
#pragma unroll
        for (int db = 0; db < 4; ++db) {
            const bf16x8 bfr = *reinterpret_cast<const bf16x8*>(WTb + db * 16 * 64 + ks * 32);
            acc[db] = __builtin_amdgcn_mfma_f32_16x16x32_bf16(af, bfr, acc[db], 0, 0, 0);
        }
    }
    const int node_base = blockIdx.x * 64 + w * 16 + g4 * 4;
#pragma unroll
    for (int db = 0; db < 4; ++db) {
        const int d = db * 16 + l15;
        const float bias = bv[d];
#pragma unroll
        for (int r = 0; r < 4; ++r) {
            const int nn = node_base + r;
            if (nn < n) xv[(size_t)nn * 64 + d] = f2bf(acc[db][r] + bias);
        }
    }
}

// ---------------------------------------------------------------------------
// SAGE layer-0 (MFMA): out[r] = act( [ x[self[r]] | mean_j xv[neigh[r,j]] ] @ Ww0 + bw0 )
// nrows must be a multiple of 64.
// ---------------------------------------------------------------------------
__global__ __launch_bounds__(256) void sage_mfma_kernel(
    const uint16_t* __restrict__ x, const uint16_t* __restrict__ xv,
    const int* __restrict__ self_idx, const int* __restrict__ neigh_idx,
    const uint16_t* __restrict__ WwT, const float* __restrict__ bw,
    uint16_t* __restrict__ out, int relu)
{
    const int t = threadIdx.x;
    const int w = t >> 6, l = t & 63, l15 = l & 15, g4 = l >> 4;
    const int r = blockIdx.x * 64 + w * 16 + l15;
    const int sidx = self_idx[r];
    const int* ni = neigh_idx + (size_t)r * S_NB;

    f32x4 acc[4] = {};
    const uint16_t* WTb = WwT + l15 * 128 + g4 * 8;

    auto MM = [&](bf16x8 af, int kb) {
#pragma unroll
        for (int db = 0; db < 4; ++db) {
            const bf16x8 bfr = *reinterpret_cast<const bf16x8*>(WTb + db * 16 * 128 + kb);
            acc[db] = __builtin_amdgcn_mfma_f32_16x16x32_bf16(af, bfr, acc[db], 0, 0, 0);
        }
    };

    // self segment k' 0..64
#pragma unroll
    for (int ks = 0; ks < 2; ++ks) {
        const bf16x8 af = *reinterpret_cast<const bf16x8*>(x + (size_t)sidx * 64 + ks * 32 + g4 * 8);
        MM(af, ks * 32);
    }
    // agg segment k' 64..128: fp32 mean of 20 bf16x8 rows of xv
#pragma unroll
    for (int ks = 0; ks < 2; ++ks) {
        float ev[4] = {0.f, 0.f, 0.f, 0.f}, od[4] = {0.f, 0.f, 0.f, 0.f};
#pragma unroll
        for (int j = 0; j < S_NB; ++j) {
            const u32x4 v = *reinterpret_cast<const u32x4*>(xv + (size_t)ni[j] * 64 + ks * 32 + g4 * 8);
#pragma unroll
            for (int q = 0; q < 4; ++q) {
                ev[q] += __uint_as_float(v[q] << 16);
                od[q] += __uint_as_float(v[q] & 0xffff0000u);
            }
        }
        BF8 m;
#pragma unroll
        for (int q = 0; q < 4; ++q) m.u[q] = pack2bf(ev[q] * (1.f / S_NB), od[q] * (1.f / S_NB));
        MM(m.v, 64 + ks * 32);
    }

    const int rb = blockIdx.x * 64 + w * 16 + g4 * 4;
#pragma unroll
    for (int db = 0; db < 4; ++db) {
        const int d = db * 16 + l15;
        const float bias = bw[d];
#pragma unroll
        for (int rr = 0; rr < 4; ++rr) {
            float h = acc[db][rr] + bias;
            if (relu) h = fmaxf(h, 0.f);
            out[(size_t)(rb + rr) * 64 + d] = f2bf(h);
        }
    }
}

// ---------------------------------------------------------------------------
// Final layer (fp32 shfl GEMV, 2048 rows):
// out[b] = [ h0[b] | (mean_s h1[b,s]) @ Wv1 + bv1 ] @ Ww1 + bw1
// ---------------------------------------------------------------------------
__global__ __launch_bounds__(256) void final_kernel(
    const uint16_t* __restrict__ h0, const uint16_t* __restrict__ h1,
    const float* __restrict__ Wv, const float* __restrict__ bv,
    const float* __restrict__ Ww, const float* __restrict__ bw,
    float* __restrict__ out)
{
    __shared__ float WvL[64 * 64];
    __shared__ float WwL[128 * 64];
    const int t = threadIdx.x;
    for (int i = t; i < 64 * 64; i += 256)  WvL[i] = Wv[i];
    for (int i = t; i < 128 * 64; i += 256) WwL[i] = Ww[i];
    __syncthreads();

    const int wave = t >> 6, lane = t & 63;
    const int base = blockIdx.x * 32 + wave * 8;
    const float bvl = bv[lane], bwl = bw[lane];

    for (int i = 0; i < 8; ++i) {
        const int b = base + i;
        float m = 0.f;
#pragma unroll
        for (int s = 0; s < S_NB; ++s)
            m += bf2f(h1[(size_t)(b * S_NB + s) * 64 + lane]);
        m *= (1.f / S_NB);

        float agg = bvl;
#pragma unroll 8
        for (int k = 0; k < 64; ++k)
            agg += __shfl(m, k) * WvL[k * 64 + lane];

        const float selfv = bf2f(h0[(size_t)b * 64 + lane]);
        float h = bwl;
#pragma unroll 8
        for (int k = 0; k < 64; ++k)
            h += __shfl(selfv, k) * WwL[k * 64 + lane];
#pragma unroll 8
        for (int k = 0; k < 64; ++k)
            h += __shfl(agg, k) * WwL[(64 + k) * 64 + lane];

        out[(size_t)b * 64 + lane] = h;
    }
}

// ---------------------------------------------------------------------------
extern "C" void kernel_launch(void* const* d_in, const int* in_sizes, int n_in,
                              void* d_out, int out_size, void* d_ws, size_t ws_size,
                              hipStream_t stream)
{
    const int*   seeds   = (const int*)d_in[0];
    const int*   neigh1  = (const int*)d_in[1];
    const int*   neigh2  = (const int*)d_in[2];
    const int*   ufi     = (const int*)d_in[3];
    const int*   ifi     = (const int*)d_in[4];
    const int*   uti     = (const int*)d_in[5];
    const int*   iti     = (const int*)d_in[6];
    const float* u_id    = (const float*)d_in[7];
    const float* i_id    = (const float*)d_in[8];
    const float* ufe     = (const float*)d_in[9];
    const float* ife     = (const float*)d_in[10];
    const float* wemb    = (const float*)d_in[11];
    const float* uw300   = (const float*)d_in[12];
    const float* iw300   = (const float*)d_in[13];
    const float* is768   = (const float*)d_in[14];
    const float* unum    = (const float*)d_in[15];
    const float* inum    = (const float*)d_in[16];
    const float* Wnum_u  = (const float*)d_in[17];
    const float* bnum_u  = (const float*)d_in[18];
    const float* Wnum_i  = (const float*)d_in[19];
    const float* bnum_i  = (const float*)d_in[20];
    const float* Wproj_u = (const float*)d_in[21];
    const float* bproj_u = (const float*)d_in[22];
    const float* Wproj_i = (const float*)d_in[23];
    const float* bproj_i = (const float*)d_in[24];
    const float* W_w     = (const float*)d_in[25];
    const float* b_w     = (const float*)d_in[26];
    const float* W_v     = (const float*)d_in[27];
    const float* b_v     = (const float*)d_in[28];

    // ws layout (uint16 elements)
    uint16_t* WTU  = (uint16_t*)d_ws;                       // 64*576
    uint16_t* WTI  = WTU  + 36864;                          // 64*1344
    uint16_t* WvT0 = WTI  + 86016;                          // 64*64
    uint16_t* WwT0 = WvT0 + 4096;                           // 64*128
    uint16_t* xbf  = WwT0 + 8192;                           // N_NODE*64
    uint16_t* xvbf = xbf  + (size_t)N_NODE * 64;            // N_NODE*64
    uint16_t* h1bf = xvbf + (size_t)N_NODE * 64;            // 40960*64
    uint16_t* h0bf = h1bf + (size_t)B_SEED * S_NB * 64;     // 2048*64
    float* outp = (float*)d_out;

    wtprep_kernel<<<144, 256, 0, stream>>>(Wproj_u, Wnum_u, WTU, 576);
    wtprep_kernel<<<336, 256, 0, stream>>>(Wproj_i, Wnum_i, WTI, 1344);
    smallprep_kernel<<<48, 256, 0, stream>>>(W_v, W_w, WvT0, WwT0);

    proj_kernel<0><<<(N_USER + 63) / 64, 256, 0, stream>>>(
        u_id, ufi, ufe, uti, wemb, uw300, nullptr, unum,
        WTU, bproj_u, bnum_u, xbf, N_USER);
    proj_kernel<1><<<(M_ITEM + 63) / 64, 256, 0, stream>>>(
        i_id, ifi, ife, iti, wemb, iw300, is768, inum,
        WTI, bproj_i, bnum_i, xbf + (size_t)N_USER * 64, M_ITEM);

    xv_kernel<<<(N_NODE + 63) / 64, 256, 0, stream>>>(xbf, WvT0, b_v, xvbf, N_NODE);

    sage_mfma_kernel<<<(B_SEED * S_NB) / 64, 256, 0, stream>>>(
        xbf, xvbf, neigh1, neigh2, WwT0, b_w, h1bf, 1);
    sage_mfma_kernel<<<B_SEED / 64, 256, 0, stream>>>(
        xbf, xvbf, seeds, neigh1, WwT0, b_w, h0bf, 1);

    final_kernel<<<B_SEED / 32, 256, 0, stream>>>(
        h0bf, h1bf, W_v + 4096, b_v + 64, W_w + 8192, b_w + 64, outp);
}

// Round 5
// 372.028 us; speedup vs baseline: 24.2202x; 1.1794x over previous
//
#include <hip/hip_runtime.h>
#include <stdint.h>

#define N_USER 100000
#define M_ITEM 50000
#define N_NODE 150000
#define B_SEED 2048
#define S_NB 20
#define UBLK 6250            // N_USER/16
#define IBLK 3125            // M_ITEM/16

typedef __bf16   bf16x8 __attribute__((ext_vector_type(8)));
typedef float    f32x4  __attribute__((ext_vector_type(4)));
typedef uint32_t u32x4  __attribute__((ext_vector_type(4)));

__device__ __forceinline__ uint16_t f2bf(float f) {
    uint32_t u = __float_as_uint(f);
    return (uint16_t)((u + 0x7FFFu + ((u >> 16) & 1u)) >> 16);   // RNE
}
__device__ __forceinline__ uint32_t pack2bf(float a, float b) {
    return (uint32_t)f2bf(a) | ((uint32_t)f2bf(b) << 16);
}
__device__ __forceinline__ float bf2f(uint16_t u) {
    return __uint_as_float(((uint32_t)u) << 16);
}

union BF8 { bf16x8 v; uint32_t u[4]; };

__device__ __forceinline__ bf16x8 pack8(const float4 lo, const float4 hi) {
    BF8 r;
    r.u[0] = pack2bf(lo.x, lo.y); r.u[1] = pack2bf(lo.z, lo.w);
    r.u[2] = pack2bf(hi.x, hi.y); r.u[3] = pack2bf(hi.z, hi.w);
    return r.v;
}
// exact masked fragment (K-tails where W is nonzero, placement matters)
__device__ __forceinline__ bf16x8 ldf32x8_mask(const float* rowp, int base, int limit) {
    BF8 r;
#pragma unroll
    for (int h = 0; h < 4; ++h) {
        const int k0 = base + 2 * h;
        const float a = (k0     < limit) ? rowp[k0]     : 0.f;
        const float b = (k0 + 1 < limit) ? rowp[k0 + 1] : 0.f;
        r.u[h] = pack2bf(a, b);
    }
    return r.v;
}

// ---------------------------------------------------------------------------
// One fused prep launch:
//  [0,36864)        WTU  (users, KPADP=576)
//  [36864,122880)   WTI  (items, KPADP=1344)
//  [122880,135168)  WvT0 (64x64) + WwT0 (64x128)
// Permuted K: [0,64) feat | [64,160) text | [160,224) id | [224,256) numeric
//             | [256,576) word300 | [576,1344) sent768 (items)
// ---------------------------------------------------------------------------
__global__ void prep_kernel(const float* __restrict__ Wproj_u, const float* __restrict__ Wnum_u,
                            const float* __restrict__ Wproj_i, const float* __restrict__ Wnum_i,
                            const float* __restrict__ Wv0, const float* __restrict__ Ww0,
                            uint16_t* __restrict__ WTU, uint16_t* __restrict__ WTI,
                            uint16_t* __restrict__ WvT, uint16_t* __restrict__ WwT)
{
    const int idx = blockIdx.x * 256 + threadIdx.x;
    if (idx < 36864) {
        const int d = idx / 576, kp = idx - d * 576;
        float v = 0.f;
        if (kp < 160)      v = Wproj_u[(64 + kp) * 64 + d];
        else if (kp < 224) v = Wproj_u[(kp - 160) * 64 + d];
        else if (kp < 256) { const int j = kp - 224; if (j < 10)  v = Wnum_u[j * 64 + d]; }
        else               { const int j = kp - 256; if (j < 300) v = Wproj_u[(224 + j) * 64 + d]; }
        WTU[d * 576 + kp] = f2bf(v);
    } else if (idx < 122880) {
        const int i2 = idx - 36864;
        const int d = i2 / 1344, kp = i2 - d * 1344;
        float v = 0.f;
        if (kp < 160)      v = Wproj_i[(64 + kp) * 64 + d];
        else if (kp < 224) v = Wproj_i[(kp - 160) * 64 + d];
        else if (kp < 256) { const int j = kp - 224; if (j < 10)  v = Wnum_i[j * 64 + d]; }
        else if (kp < 576) { const int j = kp - 256; if (j < 300) v = Wproj_i[(224 + j) * 64 + d]; }
        else               { const int j = kp - 576; v = Wproj_i[(524 + j) * 64 + d]; }
        WTI[d * 1344 + kp] = f2bf(v);
    } else {
        const int i2 = idx - 122880;
        if (i2 < 4096) { const int d = i2 >> 6, k = i2 & 63;  WvT[d * 64 + k]  = f2bf(Wv0[k * 64 + d]); }
        else           { const int j = i2 - 4096;
                         const int d = j >> 7, k = j & 127;   WwT[d * 128 + k] = f2bf(Ww0[k * 64 + d]); }
    }
}

// ---------------------------------------------------------------------------
// Fused projection, K-split: block = 16 nodes, wave w handles k-steps
// ks ≡ w (mod 4); f32 partials reduced via LDS. Users+items in one grid.
// k-step map: 0,1 feat | 2,3,4 text | 5,6 id | 7 numeric | 8..17 word300
//             | 18..41 sent768 (items). kb = ks*32 in permuted WT.
// ---------------------------------------------------------------------------
__global__ __launch_bounds__(256, 4) void proj_kernel(
    const float* __restrict__ u_id,  const int* __restrict__ ufi,
    const float* __restrict__ ufe,   const int* __restrict__ uti,
    const float* __restrict__ i_id,  const int* __restrict__ ifi,
    const float* __restrict__ ife,   const int* __restrict__ iti,
    const float* __restrict__ word_emb,
    const float* __restrict__ uw300, const float* __restrict__ iw300,
    const float* __restrict__ is768,
    const float* __restrict__ unum,  const float* __restrict__ inum,
    const uint16_t* __restrict__ WTU, const uint16_t* __restrict__ WTI,
    const float* __restrict__ bproj_u, const float* __restrict__ bnum_u,
    const float* __restrict__ bproj_i, const float* __restrict__ bnum_i,
    uint16_t* __restrict__ xout)
{
    __shared__ float R[4 * 16 * 64];   // 16 KB: [wave][node16][dim]

    const int t = threadIdx.x;
    const int w = t >> 6, l = t & 63;
    const int l15 = l & 15, g4 = l >> 4;
    const bool item = blockIdx.x >= UBLK;
    const int tile = item ? (blockIdx.x - UBLK) : blockIdx.x;
    const int nloc = tile * 16 + l15;          // node within its type

    const float* id_emb   = item ? i_id  : u_id;
    const int*   feat_idx = item ? ifi   : ufi;
    const float* feat_emb = item ? ife   : ufe;
    const int*   text_idx = item ? iti   : uti;
    const float* word300  = item ? iw300 : uw300;
    const float* numeric  = item ? inum  : unum;
    const uint16_t* WT    = item ? WTI   : WTU;
    const int KPADP       = item ? 1344  : 576;

    f32x4 acc[4] = {};
    const uint16_t* WTp[4];
#pragma unroll
    for (int db = 0; db < 4; ++db)
        WTp[db] = WT + (size_t)(db * 16 + l15) * KPADP + g4 * 8;

    auto MM = [&](bf16x8 af, int kb) {
#pragma unroll
        for (int db = 0; db < 4; ++db) {
            const bf16x8 bfr = *reinterpret_cast<const bf16x8*>(WTp[db] + kb);
            acc[db] = __builtin_amdgcn_mfma_f32_16x16x32_bf16(af, bfr, acc[db], 0, 0, 0);
        }
    };

    // ---- feat: ks 0 (w0), 1 (w1) ----
    if (w < 2) {
        const int* fip = feat_idx + (size_t)nloc * 10;
        int fi[10];
#pragma unroll
        for (int j = 0; j < 10; ++j) fi[j] = fip[j];
        float4 s0 = make_float4(0.f, 0.f, 0.f, 0.f);
        float4 s1 = make_float4(0.f, 0.f, 0.f, 0.f);
#pragma unroll
        for (int j = 0; j < 10; ++j) {
            const float* rp = feat_emb + (size_t)fi[j] * 64 + w * 32 + g4 * 8;
            const float4 a = *(const float4*)rp;
            const float4 b = *(const float4*)(rp + 4);
            s0.x += a.x; s0.y += a.y; s0.z += a.z; s0.w += a.w;
            s1.x += b.x; s1.y += b.y; s1.z += b.z; s1.w += b.w;
        }
        MM(pack8(make_float4(s0.x * 0.1f, s0.y * 0.1f, s0.z * 0.1f, s0.w * 0.1f),
                 make_float4(s1.x * 0.1f, s1.y * 0.1f, s1.z * 0.1f, s1.w * 0.1f)),
           w * 32);
    }

    // ---- text: ks2->w2 (src0), ks3->w3 (src1), ks4->w0 (src2) ----
    {
        const int src = (w == 2) ? 0 : (w == 3) ? 1 : (w == 0) ? 2 : -1;
        if (src >= 0) {
            const int* tip = text_idx + ((size_t)nloc * 3 + src) * 8;
            int tok[8];
#pragma unroll
            for (int j = 0; j < 8; ++j) tok[j] = tip[j];
            float4 s0 = make_float4(0.f, 0.f, 0.f, 0.f);
            float4 s1 = make_float4(0.f, 0.f, 0.f, 0.f);
#pragma unroll
            for (int j = 0; j < 8; ++j) {
                const float* rp = word_emb + (size_t)tok[j] * 32 + g4 * 8;
                const float4 a = *(const float4*)rp;
                const float4 b = *(const float4*)(rp + 4);
                s0.x += a.x; s0.y += a.y; s0.z += a.z; s0.w += a.w;
                s1.x += b.x; s1.y += b.y; s1.z += b.z; s1.w += b.w;
            }
            MM(pack8(make_float4(s0.x * 0.125f, s0.y * 0.125f, s0.z * 0.125f, s0.w * 0.125f),
                     make_float4(s1.x * 0.125f, s1.y * 0.125f, s1.z * 0.125f, s1.w * 0.125f)),
               (2 + src) * 32);
        }
    }

    // ---- id: ks5 (w1), ks6 (w2) ----
    if (w == 1 || w == 2) {
        const int half = w - 1;
        const float* p = id_emb + (size_t)nloc * 64 + half * 32 + g4 * 8;
        MM(pack8(*(const float4*)p, *(const float4*)(p + 4)), (5 + half) * 32);
    }

    // ---- numeric: ks7 (w3) ----
    if (w == 3)
        MM(ldf32x8_mask(numeric + (size_t)nloc * 10, g4 * 8, 10), 7 * 32);

    // ---- word300: ks = 8+w, 12+w, 16+w (ks17 = masked tail) ----
    {
        const float* wr = word300 + (size_t)nloc * 300;
        float4 va[3][2];
#pragma unroll
        for (int i = 0; i < 3; ++i) {
            const int ks = 8 + w + 4 * i;
            if (ks < 17) {
                const float* p = wr + (ks - 8) * 32 + g4 * 8;
                va[i][0] = *(const float4*)p;
                va[i][1] = *(const float4*)(p + 4);
            }
        }
#pragma unroll
        for (int i = 0; i < 3; ++i) {
            const int ks = 8 + w + 4 * i;
            if (ks < 17)       MM(pack8(va[i][0], va[i][1]), ks * 32);
            else if (ks == 17) MM(ldf32x8_mask(wr, 288 + g4 * 8, 300), 17 * 32);
        }
    }

    // ---- sent768 (items): ks = 18 + w + 4i, i<6 ----
    if (item) {
        const float* sr = is768 + (size_t)nloc * 768;
        float4 va[6][2];
#pragma unroll
        for (int i = 0; i < 6; ++i) {
            const float* p = sr + (w + 4 * i) * 32 + g4 * 8;
            va[i][0] = *(const float4*)p;
            va[i][1] = *(const float4*)(p + 4);
        }
#pragma unroll
        for (int i = 0; i < 6; ++i)
            MM(pack8(va[i][0], va[i][1]), (18 + w + 4 * i) * 32);
    }

    // ---- LDS reduce across waves ----
    {
        float* Rw = R + w * 1024;
#pragma unroll
        for (int db = 0; db < 4; ++db)
#pragma unroll
            for (int r = 0; r < 4; ++r)
                Rw[(g4 * 4 + r) * 64 + db * 16 + l15] = acc[db][r];
    }
    __syncthreads();

    const int n  = t >> 4;           // node 0..15
    const int dq = t & 15;           // dim quad
    const f32x4* RV = (const f32x4*)R;
    f32x4 s = RV[n * 16 + dq] + RV[256 + n * 16 + dq]
            + RV[512 + n * 16 + dq] + RV[768 + n * 16 + dq];

    const float* bp = item ? bproj_i : bproj_u;
    const float* bn = item ? bnum_i  : bnum_u;
    const float4 b1 = *(const float4*)(bp + dq * 4);
    const float4 b2 = *(const float4*)(bn + dq * 4);
    const uint32_t o0 = pack2bf(s[0] + b1.x + b2.x, s[1] + b1.y + b2.y);
    const uint32_t o1 = pack2bf(s[2] + b1.z + b2.z, s[3] + b1.w + b2.w);
    const size_t obase = ((size_t)(item ? N_USER : 0) + (size_t)tile * 16 + n) * 64 + dq * 4;
    *(uint2*)(xout + obase) = make_uint2(o0, o1);
}

// ---------------------------------------------------------------------------
// xv = x @ Wv0 + bv0   (bf16 in/out, per node)
// ---------------------------------------------------------------------------
__global__ __launch_bounds__(256) void xv_kernel(
    const uint16_t* __restrict__ x, const uint16_t* __restrict__ WvT,
    const float* __restrict__ bv, uint16_t* __restrict__ xv, int n)
{
    const int t = threadIdx.x;
    const int w = t >> 6, l = t & 63, l15 = l & 15, g4 = l >> 4;
    const int node = blockIdx.x * 64 + w * 16 + l15;
    const int node_c = node < n ? node : n - 1;

    f32x4 acc[4] = {};
    const uint16_t* WTb = WvT + l15 * 64 + g4 * 8;
#pragma unroll
    for (int ks = 0; ks < 2; ++ks) {
        const bf16x8 af = *reinterpret_cast<const bf16x8*>(x + (size_t)node_c * 64 + ks * 32 + g4 * 8);
#pragma unroll
        for (int db = 0; db < 4; ++db) {
            const bf16x8 bfr = *reinterpret_cast<const bf16x8*>(WTb + db * 16 * 64 + ks * 32);
            acc[db] = __builtin_amdgcn_mfma_f32_16x16x32_bf16(af, bfr, acc[db], 0, 0, 0);
        }
    }
    const int node_base = blockIdx.x * 64 + w * 16 + g4 * 4;
#pragma unroll
    for (int db = 0; db < 4; ++db) {
        const int d = db * 16 + l15;
        const float bias = bv[d];
#pragma unroll
        for (int r = 0; r < 4; ++r) {
            const int nn = node_base + r;
            if (nn < n) xv[(size_t)nn * 64 + d] = f2bf(acc[db][r] + bias);
        }
    }
}

// ---------------------------------------------------------------------------
// SAGE layer-0 (MFMA): out[r] = act( [ x[self[r]] | mean_j xv[neigh[r,j]] ] @ Ww0 + bw0 )
// ---------------------------------------------------------------------------
__global__ __launch_bounds__(256) void sage_mfma_kernel(
    const uint16_t* __restrict__ x, const uint16_t* __restrict__ xv,
    const int* __restrict__ self_idx, const int* __restrict__ neigh_idx,
    const uint16_t* __restrict__ WwT, const float* __restrict__ bw,
    uint16_t* __restrict__ out, int relu)
{
    const int t = threadIdx.x;
    const int w = t >> 6, l = t & 63, l15 = l & 15, g4 = l >> 4;
    const int r = blockIdx.x * 64 + w * 16 + l15;
    const int sidx = self_idx[r];
    const int* ni = neigh_idx + (size_t)r * S_NB;

    f32x4 acc[4] = {};
    const uint16_t* WTb = WwT + l15 * 128 + g4 * 8;

    auto MM = [&](bf16x8 af, int kb) {
#pragma unroll
        for (int db = 0; db < 4; ++db) {
            const bf16x8 bfr = *reinterpret_cast<const bf16x8*>(WTb + db * 16 * 128 + kb);
            acc[db] = __builtin_amdgcn_mfma_f32_16x16x32_bf16(af, bfr, acc[db], 0, 0, 0);
        }
    };

#pragma unroll
    for (int ks = 0; ks < 2; ++ks) {
        const bf16x8 af = *reinterpret_cast<const bf16x8*>(x + (size_t)sidx * 64 + ks * 32 + g4 * 8);
        MM(af, ks * 32);
    }
#pragma unroll
    for (int ks = 0; ks < 2; ++ks) {
        float ev[4] = {0.f, 0.f, 0.f, 0.f}, od[4] = {0.f, 0.f, 0.f, 0.f};
#pragma unroll
        for (int j = 0; j < S_NB; ++j) {
            const u32x4 v = *reinterpret_cast<const u32x4*>(xv + (size_t)ni[j] * 64 + ks * 32 + g4 * 8);
#pragma unroll
            for (int q = 0; q < 4; ++q) {
                ev[q] += __uint_as_float(v[q] << 16);
                od[q] += __uint_as_float(v[q] & 0xffff0000u);
            }
        }
        BF8 m;
#pragma unroll
        for (int q = 0; q < 4; ++q) m.u[q] = pack2bf(ev[q] * (1.f / S_NB), od[q] * (1.f / S_NB));
        MM(m.v, 64 + ks * 32);
    }

    const int rb = blockIdx.x * 64 + w * 16 + g4 * 4;
#pragma unroll
    for (int db = 0; db < 4; ++db) {
        const int d = db * 16 + l15;
        const float bias = bw[d];
#pragma unroll
        for (int rr = 0; rr < 4; ++rr) {
            float h = acc[db][rr] + bias;
            if (relu) h = fmaxf(h, 0.f);
            out[(size_t)(rb + rr) * 64 + d] = f2bf(h);
        }
    }
}

// ---------------------------------------------------------------------------
// Final layer (fp32 shfl GEMV, 2048 rows)
// ---------------------------------------------------------------------------
__global__ __launch_bounds__(256) void final_kernel(
    const uint16_t* __restrict__ h0, const uint16_t* __restrict__ h1,
    const float* __restrict__ Wv, const float* __restrict__ bv,
    const float* __restrict__ Ww, const float* __restrict__ bw,
    float* __restrict__ out)
{
    __shared__ float WvL[64 * 64];
    __shared__ float WwL[128 * 64];
    const int t = threadIdx.x;
    for (int i = t; i < 64 * 64; i += 256)  WvL[i] = Wv[i];
    for (int i = t; i < 128 * 64; i += 256) WwL[i] = Ww[i];
    __syncthreads();

    const int wave = t >> 6, lane = t & 63;
    const int base = blockIdx.x * 32 + wave * 8;
    const float bvl = bv[lane], bwl = bw[lane];

    for (int i = 0; i < 8; ++i) {
        const int b = base + i;
        float m = 0.f;
#pragma unroll
        for (int s = 0; s < S_NB; ++s)
            m += bf2f(h1[(size_t)(b * S_NB + s) * 64 + lane]);
        m *= (1.f / S_NB);

        float agg = bvl;
#pragma unroll 8
        for (int k = 0; k < 64; ++k)
            agg += __shfl(m, k) * WvL[k * 64 + lane];

        const float selfv = bf2f(h0[(size_t)b * 64 + lane]);
        float h = bwl;
#pragma unroll 8
        for (int k = 0; k < 64; ++k)
            h += __shfl(selfv, k) * WwL[k * 64 + lane];
#pragma unroll 8
        for (int k = 0; k < 64; ++k)
            h += __shfl(agg, k) * WwL[(64 + k) * 64 + lane];

        out[(size_t)b * 64 + lane] = h;
    }
}

// ---------------------------------------------------------------------------
extern "C" void kernel_launch(void* const* d_in, const int* in_sizes, int n_in,
                              void* d_out, int out_size, void* d_ws, size_t ws_size,
                              hipStream_t stream)
{
    const int*   seeds   = (const int*)d_in[0];
    const int*   neigh1  = (const int*)d_in[1];
    const int*   neigh2  = (const int*)d_in[2];
    const int*   ufi     = (const int*)d_in[3];
    const int*   ifi     = (const int*)d_in[4];
    const int*   uti     = (const int*)d_in[5];
    const int*   iti     = (const int*)d_in[6];
    const float* u_id    = (const float*)d_in[7];
    const float* i_id    = (const float*)d_in[8];
    const float* ufe     = (const float*)d_in[9];
    const float* ife     = (const float*)d_in[10];
    const float* wemb    = (const float*)d_in[11];
    const float* uw300   = (const float*)d_in[12];
    const float* iw300   = (const float*)d_in[13];
    const float* is768   = (const float*)d_in[14];
    const float* unum    = (const float*)d_in[15];
    const float* inum    = (const float*)d_in[16];
    const float* Wnum_u  = (const float*)d_in[17];
    const float* bnum_u  = (const float*)d_in[18];
    const float* Wnum_i  = (const float*)d_in[19];
    const float* bnum_i  = (const float*)d_in[20];
    const float* Wproj_u = (const float*)d_in[21];
    const float* bproj_u = (const float*)d_in[22];
    const float* Wproj_i = (const float*)d_in[23];
    const float* bproj_i = (const float*)d_in[24];
    const float* W_w     = (const float*)d_in[25];
    const float* b_w     = (const float*)d_in[26];
    const float* W_v     = (const float*)d_in[27];
    const float* b_v     = (const float*)d_in[28];

    // ws layout (uint16 elements)
    uint16_t* WTU  = (uint16_t*)d_ws;                       // 64*576
    uint16_t* WTI  = WTU  + 36864;                          // 64*1344
    uint16_t* WvT0 = WTI  + 86016;                          // 64*64
    uint16_t* WwT0 = WvT0 + 4096;                           // 64*128
    uint16_t* xbf  = WwT0 + 8192;                           // N_NODE*64
    uint16_t* xvbf = xbf  + (size_t)N_NODE * 64;            // N_NODE*64
    uint16_t* h1bf = xvbf + (size_t)N_NODE * 64;            // 40960*64
    uint16_t* h0bf = h1bf + (size_t)B_SEED * S_NB * 64;     // 2048*64
    float* outp = (float*)d_out;

    prep_kernel<<<528, 256, 0, stream>>>(
        Wproj_u, Wnum_u, Wproj_i, Wnum_i, W_v, W_w, WTU, WTI, WvT0, WwT0);

    proj_kernel<<<UBLK + IBLK, 256, 0, stream>>>(
        u_id, ufi, ufe, uti, i_id, ifi, ife, iti, wemb,
        uw300, iw300, is768, unum, inum,
        WTU, WTI, bproj_u, bnum_u, bproj_i, bnum_i, xbf);

    xv_kernel<<<(N_NODE + 63) / 64, 256, 0, stream>>>(xbf, WvT0, b_v, xvbf, N_NODE);

    sage_mfma_kernel<<<(B_SEED * S_NB) / 64, 256, 0, stream>>>(
        xbf, xvbf, neigh1, neigh2, WwT0, b_w, h1bf, 1);
    sage_mfma_kernel<<<B_SEED / 64, 256, 0, stream>>>(
        xbf, xvbf, seeds, neigh1, WwT0, b_w, h0bf, 1);

    final_kernel<<<B_SEED / 32, 256, 0, stream>>>(
        h0bf, h1bf, W_v + 4096, b_v + 64, W_w + 8192, b_w + 64, outp);
}